// Round 6
// baseline (226.208 us; speedup 1.0000x reference)
//
#include <hip/hip_runtime.h>

// ExLlama q4: T=32, K=8192, N=28672, group=128.
// Harness promotes fp16 reference arrays to float32; output is float32.
//
// ROUND-6: r0/r5 plateau (55/56 us GEMM at 12 vs 20 waves/CU) proves
// occupancy is not the limiter. Wave-lifetime arithmetic (14336 waves, ~5
// resident/SIMD, 56 us) gives ~20 us block lifetime == waves wait ~90% of
// life at the single __syncthreads (staging-chain convoy). This round
// removes the barrier STRUCTURALLY: a 3-us prep kernel converts x once to
// fp16 pair-permuted [i,i+4] (512 KB, L2-resident); the GEMM loads MFMA
// A-fragments directly from L2 per (g,c) step with depth-1 register
// prefetch. No LDS, no barrier, no ds ops, no pkrtz in the hot path.
// x L2 traffic = 3584 blk x 128 KB = 458 MB ~= 13 us aggregate (fine).
// Carried verbatim from passing r5: 0x6400 nibble dequant, whole-segment
// 32-reg qweight prefetch issued before everything, fp16 ws + reduce,
// MFMA 16x16x32 f16 fragment mapping, 32 cols/wave epilogue.
#define T_TOK   32
#define KDIM    8192
#define NDIM    28672
#define NZW     3584             // N / 8
#define NSEG    16               // K-segments (blockIdx.y)
#define SEGK    (KDIM / NSEG)    // 512
#define GPS     4                // quant groups per segment: SEGK/128

typedef _Float16 half8  __attribute__((ext_vector_type(8)));
typedef _Float16 half2v __attribute__((ext_vector_type(2)));
typedef float    f32x4  __attribute__((ext_vector_type(4)));
typedef unsigned uint4v __attribute__((ext_vector_type(4)));

// ---- x prep: f32 -> f16, pair-permuted [i,i+4] within each 8, [t][k] ----
__global__ __launch_bounds__(256)
void xprep(const float* __restrict__ x, _Float16* __restrict__ xp)
{
    const int idx = blockIdx.x * 256 + threadIdx.x;   // 32768 threads total
    const int t   = idx >> 10;                         // 1024 8-elem chunks/row
    const int k0  = (idx & 1023) * 8;
    const float* src = x + (size_t)t * KDIM + k0;
    f32x4 lo = *(const f32x4*)src;
    f32x4 hi = *(const f32x4*)(src + 4);
    uint4v u;
    #pragma unroll
    for (int j = 0; j < 4; ++j)
        u[j] = __builtin_bit_cast(unsigned,
                  __builtin_amdgcn_cvt_pkrtz(lo[j], hi[j]));
    *(uint4v*)(xp + (size_t)t * KDIM + k0) = u;
}

// ---- main GEMM: no LDS, no barrier; A-fragments streamed from L2 ----
__global__ __launch_bounds__(256)
void exllama_gemm_nolds(const int*      __restrict__ qweight,
                        const int*      __restrict__ qzeros,
                        const float*    __restrict__ scales,
                        const _Float16* __restrict__ xp,
                        _Float16*       __restrict__ ws)
{
    const int tid  = threadIdx.x;
    const int lane = tid & 63;
    const int wav  = tid >> 6;
    const int quad = lane >> 4;
    const int l16  = lane & 15;
    const int seg  = blockIdx.y;
    const int n0   = blockIdx.x * 128 + wav * 32;   // 32 cols per wave
    const int g0   = seg * GPS;
    const int kseg0 = seg * SEGK;

    int nc[2];
    nc[0] = n0 + l16;
    nc[1] = n0 + 16 + l16;

    // whole-segment qweight prefetch: 32 regs, all in flight first
    unsigned qw[GPS][8];
    #pragma unroll
    for (int g = 0; g < GPS; ++g) {
        const size_t rb = (size_t)((g0 + g) * 16 + quad) * NDIM;
        #pragma unroll
        for (int c = 0; c < 4; ++c)
            #pragma unroll
            for (int j = 0; j < 2; ++j)
                qw[g][c * 2 + j] = (unsigned)qweight[rb + (size_t)(c * 4) * NDIM + nc[j]];
    }

    // raw scales/zeros (loads only; convert later)
    float sraw[GPS][2];
    int   zraw[GPS][2];
    #pragma unroll
    for (int g = 0; g < GPS; ++g)
        #pragma unroll
        for (int j = 0; j < 2; ++j) {
            sraw[g][j] = scales[(size_t)(g0 + g) * NDIM + nc[j]];
            zraw[g][j] = qzeros[(size_t)(g0 + g) * NZW + (nc[j] >> 3)];
        }

    // A-fragment row pointers (this lane reads rows l16 and l16+16)
    const _Float16* xr0 = xp + (size_t)l16 * KDIM + kseg0 + quad * 8;
    const _Float16* xr1 = xr0 + (size_t)16 * KDIM;

    // convert scales/zeros
    half2v sp[GPS][2], cp[GPS][2];
    #pragma unroll
    for (int g = 0; g < GPS; ++g)
        #pragma unroll
        for (int j = 0; j < 2; ++j) {
            const int z = (zraw[g][j] >> ((nc[j] & 7) * 4)) & 15;
            const _Float16 sh = (_Float16)sraw[g][j];
            const _Float16 ch = (_Float16)(float)(-(1025 + z));
            sp[g][j] = (half2v){sh, sh};
            cp[g][j] = (half2v){ch, ch};
        }

    f32x4 acc[2][2];
    #pragma unroll
    for (int j = 0; j < 2; ++j)
        #pragma unroll
        for (int m = 0; m < 2; ++m)
            acc[j][m] = (f32x4){0.f, 0.f, 0.f, 0.f};

    // compute: depth-1 register prefetch of A-fragments from L2
    half8 a0 = *(const half8*)(xr0);
    half8 a1 = *(const half8*)(xr1);
    #pragma unroll
    for (int g = 0; g < GPS; ++g) {
        #pragma unroll
        for (int c = 0; c < 4; ++c) {
            const half8 ca0 = a0;
            const half8 ca1 = a1;
            const int nx = g * 4 + c + 1;               // next (g,c) step
            if (nx < 16) {
                const int kn = (nx >> 2) * 128 + (nx & 3) * 32;
                a0 = *(const half8*)(xr0 + kn);
                a1 = *(const half8*)(xr1 + kn);
            }
            #pragma unroll
            for (int j = 0; j < 2; ++j) {
                const unsigned w = qw[g][c * 2 + j];
                uint4v bu;
                #pragma unroll
                for (int i = 0; i < 4; ++i) {
                    unsigned t = ((w >> (4 * i)) & 0x000F000Fu) | 0x64006400u;
                    half2v th = __builtin_bit_cast(half2v, t);
                    half2v r  = (th + cp[g][j]) * sp[g][j];
                    bu[i] = __builtin_bit_cast(unsigned, r);
                }
                half8 bf = __builtin_bit_cast(half8, bu);
                acc[j][0] = __builtin_amdgcn_mfma_f32_16x16x32_f16(ca0, bf, acc[j][0], 0, 0, 0);
                acc[j][1] = __builtin_amdgcn_mfma_f32_16x16x32_f16(ca1, bf, acc[j][1], 0, 0, 0);
            }
        }
    }

    // epilogue: fp16 partials to ws
    _Float16* wsp = ws + (size_t)seg * (T_TOK * NDIM);
    #pragma unroll
    for (int j = 0; j < 2; ++j)
        #pragma unroll
        for (int m = 0; m < 2; ++m)
            #pragma unroll
            for (int r = 0; r < 4; ++r) {
                const int t = m * 16 + quad * 4 + r;
                wsp[(size_t)t * NDIM + nc[j]] = (_Float16)acc[j][m][r];
            }
}

__global__ __launch_bounds__(256)
void reduce_bias(const _Float16* __restrict__ ws,
                 const float*    __restrict__ bias,
                 float*          __restrict__ out)
{
    const int e = (blockIdx.x * 256 + threadIdx.x) * 8;  // 8 consecutive, one row
    const int n = e % NDIM;
    float sum[8] = {0.f, 0.f, 0.f, 0.f, 0.f, 0.f, 0.f, 0.f};
    #pragma unroll
    for (int s = 0; s < NSEG; ++s) {
        half8 v = *(const half8*)(ws + (size_t)s * (T_TOK * NDIM) + e);
        #pragma unroll
        for (int i = 0; i < 8; ++i) sum[i] += (float)v[i];
    }
    f32x4 o0, o1;
    #pragma unroll
    for (int i = 0; i < 4; ++i) {
        o0[i] = sum[i]     + bias[n + i];
        o1[i] = sum[i + 4] + bias[n + 4 + i];
    }
    *(f32x4*)(out + e)     = o0;
    *(f32x4*)(out + e + 4) = o1;
}

// ---- fallback (no usable ws): r5's single-barrier LDS kernel, atomics ----
__global__ __launch_bounds__(256)
void exllama_gemm_atomic(const int*   __restrict__ qweight,
                         const int*   __restrict__ qzeros,
                         const float* __restrict__ scales,
                         const float* __restrict__ x,
                         const float* __restrict__ bias,
                         float*       __restrict__ out)
{
    __shared__ alignas(16) _Float16 xs[T_TOK * SEGK];   // 32768 B
    char* xb = (char*)xs;

    const int tid  = threadIdx.x;
    const int lane = tid & 63;
    const int wav  = tid >> 6;
    const int quad = lane >> 4;
    const int l16  = lane & 15;
    const int seg  = blockIdx.y;
    const int n0   = blockIdx.x * 128 + wav * 32;
    const int g0   = seg * GPS;

    int nc[2];
    nc[0] = n0 + l16;
    nc[1] = n0 + 16 + l16;

    unsigned qw[GPS][8];
    #pragma unroll
    for (int g = 0; g < GPS; ++g) {
        const size_t rb = (size_t)((g0 + g) * 16 + quad) * NDIM;
        #pragma unroll
        for (int c = 0; c < 4; ++c)
            #pragma unroll
            for (int j = 0; j < 2; ++j)
                qw[g][c * 2 + j] = (unsigned)qweight[rb + (size_t)(c * 4) * NDIM + nc[j]];
    }
    float sraw[GPS][2];
    int   zraw[GPS][2];
    #pragma unroll
    for (int g = 0; g < GPS; ++g)
        #pragma unroll
        for (int j = 0; j < 2; ++j) {
            sraw[g][j] = scales[(size_t)(g0 + g) * NDIM + nc[j]];
            zraw[g][j] = qzeros[(size_t)(g0 + g) * NZW + (nc[j] >> 3)];
        }
    {
        const int kseg0 = seg * SEGK;
        #pragma unroll
        for (int it = 0; it < 8; ++it) {
            const int e  = it * 2048 + tid * 8;
            const int t  = e >> 9;
            const int kl = e & (SEGK - 1);
            const float* xpr = x + (size_t)t * KDIM + kseg0 + kl;
            f32x4 lo = *(const f32x4*)xpr;
            f32x4 hi = *(const f32x4*)(xpr + 4);
            uint4v u;
            #pragma unroll
            for (int j = 0; j < 4; ++j)
                u[j] = __builtin_bit_cast(unsigned,
                          __builtin_amdgcn_cvt_pkrtz(lo[j], hi[j]));
            const int off = (t * 1024 + kl * 2) ^ ((t & 7) << 4);
            *(uint4v*)(xb + off) = u;
        }
    }
    half2v sp[GPS][2], cp[GPS][2];
    #pragma unroll
    for (int g = 0; g < GPS; ++g)
        #pragma unroll
        for (int j = 0; j < 2; ++j) {
            const int z = (zraw[g][j] >> ((nc[j] & 7) * 4)) & 15;
            const _Float16 sh = (_Float16)sraw[g][j];
            const _Float16 ch = (_Float16)(float)(-(1025 + z));
            sp[g][j] = (half2v){sh, sh};
            cp[g][j] = (half2v){ch, ch};
        }
    __syncthreads();

    f32x4 acc[2][2];
    #pragma unroll
    for (int j = 0; j < 2; ++j)
        #pragma unroll
        for (int m = 0; m < 2; ++m)
            acc[j][m] = (f32x4){0.f, 0.f, 0.f, 0.f};
    #pragma unroll
    for (int g = 0; g < GPS; ++g) {
        #pragma unroll
        for (int c = 0; c < 4; ++c) {
            const int kloc = g * 128 + c * 32 + quad * 8;
            const int o0 = (l16 * 1024 + kloc * 2) ^ ((l16 & 7) << 4);
            half8 a0 = *(const half8*)(xb + o0);
            half8 a1 = *(const half8*)(xb + o0 + 16 * 1024);
            #pragma unroll
            for (int j = 0; j < 2; ++j) {
                const unsigned w = qw[g][c * 2 + j];
                uint4v bu;
                #pragma unroll
                for (int i = 0; i < 4; ++i) {
                    unsigned t = ((w >> (4 * i)) & 0x000F000Fu) | 0x64006400u;
                    half2v th = __builtin_bit_cast(half2v, t);
                    half2v r  = (th + cp[g][j]) * sp[g][j];
                    bu[i] = __builtin_bit_cast(unsigned, r);
                }
                half8 bf = __builtin_bit_cast(half8, bu);
                acc[j][0] = __builtin_amdgcn_mfma_f32_16x16x32_f16(a0, bf, acc[j][0], 0, 0, 0);
                acc[j][1] = __builtin_amdgcn_mfma_f32_16x16x32_f16(a1, bf, acc[j][1], 0, 0, 0);
            }
        }
    }
    #pragma unroll
    for (int j = 0; j < 2; ++j) {
        const float bb = bias[nc[j]] * (1.0f / NSEG);
        #pragma unroll
        for (int m = 0; m < 2; ++m)
            #pragma unroll
            for (int r = 0; r < 4; ++r) {
                const int t = m * 16 + quad * 4 + r;
                unsafeAtomicAdd(out + (size_t)t * NDIM + nc[j], acc[j][m][r] + bb);
            }
    }
}

extern "C" void kernel_launch(void* const* d_in, const int* in_sizes, int n_in,
                              void* d_out, int out_size, void* d_ws, size_t ws_size,
                              hipStream_t stream)
{
    const float* x  = (const float*)d_in[0];   // (32, 8192) f32 (fp16 promoted)
    const int* qweight = (const int*)d_in[1];  // (1024, 28672) i32
    const int* qzeros  = (const int*)d_in[2];  // (64, 3584) i32
    const float* sc = (const float*)d_in[3];   // (64, 28672) f32
    const float* bs = (const float*)d_in[4];   // (28672,) f32
    float* out      = (float*)d_out;           // (32, 28672) f32

    const size_t xpbytes = (size_t)T_TOK * KDIM * sizeof(_Float16);        // 512 KB
    const size_t pbytes  = (size_t)NSEG * T_TOK * NDIM * sizeof(_Float16); // 29.4 MB
    if (ws_size >= xpbytes + pbytes) {
        _Float16* xp   = (_Float16*)d_ws;
        _Float16* part = xp + (size_t)T_TOK * KDIM;
        xprep<<<(T_TOK * KDIM / 8) / 256, 256, 0, stream>>>(x, xp);
        exllama_gemm_nolds<<<dim3(NDIM / 128, NSEG), 256, 0, stream>>>(
            qweight, qzeros, sc, xp, part);
        reduce_bias<<<(T_TOK * NDIM) / (256 * 8), 256, 0, stream>>>(
            part, bs, out);
    } else {
        exllama_gemm_atomic<<<dim3(NDIM / 128, NSEG), 256, 0, stream>>>(
            qweight, qzeros, sc, x, bs, out);
    }
}

// Round 7
// 199.177 us; speedup vs baseline: 1.1357x; 1.1357x over previous
//
#include <hip/hip_runtime.h>

// ExLlama q4: T=32, K=8192, N=28672, group=128.
// Harness promotes fp16 reference arrays to float32; output is float32.
//
// ROUND-7: r6 falsified the barrier-convoy theory (no-LDS = 86us, exposed
// L2 latency) but exposed the real defect: VGPR_Count 48-64 across ALL
// rounds => the compiler has been SINKING the "deep prefetch" loads to
// their uses (the designed schedule never existed in emitted code), and
// achieved occupancy sat at ~2.5 waves/SIMD regardless of nominal.
// This round makes the prefetch actually fit:
//  - x staged via global_load_lds (16B) from a pre-converted fp16 xp
//    (xprep kernel, 512KB, L2-resident): 8 insts/thread, ZERO staging
//    VALU and ZERO staging VGPRs (was ~36 regs + 48 insts through regs).
//    Swizzle kept by pre-swizzling the per-lane GLOBAL src chunk
//    (v = c ^ ((c>>6)&7)); LDS dest stays linear (HW requirement);
//    compute reads with the same XOR as r5 -> bit-identical layout.
//  - qw 32-reg whole-segment prefetch + sched_barrier(0) pin; total live
//    ~90 VGPR so it can genuinely stay resident. No launch_bounds cap
//    (r4 spill lesson).
// Carried verbatim (pass-verified): 0x6400 nibble dequant, MFMA 16x16x32
// f16 mapping, fp16 ws + reduce, 32 cols/wave, XOR-swizzled 32KB LDS.
#define T_TOK   32
#define KDIM    8192
#define NDIM    28672
#define NZW     3584             // N / 8
#define NSEG    16               // K-segments (blockIdx.y)
#define SEGK    (KDIM / NSEG)    // 512
#define GPS     4                // quant groups per segment: SEGK/128

typedef _Float16 half8  __attribute__((ext_vector_type(8)));
typedef _Float16 half2v __attribute__((ext_vector_type(2)));
typedef float    f32x4  __attribute__((ext_vector_type(4)));
typedef unsigned uint4v __attribute__((ext_vector_type(4)));

typedef const __attribute__((address_space(1))) void gas_void;
typedef __attribute__((address_space(3))) void       las_void;

// ---- x prep: f32 -> f16, pair-permuted [i,i+4] within each 8, [t][k] ----
__global__ __launch_bounds__(256)
void xprep(const float* __restrict__ x, _Float16* __restrict__ xp)
{
    const int idx = blockIdx.x * 256 + threadIdx.x;   // 32768 threads total
    const int t   = idx >> 10;                         // 1024 8-elem chunks/row
    const int k0  = (idx & 1023) * 8;
    const float* src = x + (size_t)t * KDIM + k0;
    f32x4 lo = *(const f32x4*)src;
    f32x4 hi = *(const f32x4*)(src + 4);
    uint4v u;
    #pragma unroll
    for (int j = 0; j < 4; ++j)
        u[j] = __builtin_bit_cast(unsigned,
                  __builtin_amdgcn_cvt_pkrtz(lo[j], hi[j]));
    *(uint4v*)(xp + (size_t)t * KDIM + k0) = u;
}

// ---- main GEMM: global_load_lds x staging, register qweight prefetch ----
__global__ __launch_bounds__(256)
void exllama_gemm_glds(const int*      __restrict__ qweight,
                       const int*      __restrict__ qzeros,
                       const float*    __restrict__ scales,
                       const _Float16* __restrict__ xp,
                       _Float16*       __restrict__ ws)
{
    __shared__ alignas(16) _Float16 xs[T_TOK * SEGK];   // 32768 B exactly
    char* xb = (char*)xs;

    const int tid  = threadIdx.x;
    const int lane = tid & 63;
    const int wav  = tid >> 6;
    const int quad = lane >> 4;
    const int l16  = lane & 15;
    const int seg  = blockIdx.y;
    const int n0   = blockIdx.x * 128 + wav * 32;   // 32 cols per wave
    const int g0   = seg * GPS;
    const int kseg0 = seg * SEGK;

    int nc[2];
    nc[0] = n0 + l16;
    nc[1] = n0 + 16 + l16;

    // whole-segment qweight prefetch: 32 regs, all issued first
    unsigned qw[GPS][8];
    #pragma unroll
    for (int g = 0; g < GPS; ++g) {
        const size_t rb = (size_t)((g0 + g) * 16 + quad) * NDIM;
        #pragma unroll
        for (int c = 0; c < 4; ++c)
            #pragma unroll
            for (int j = 0; j < 2; ++j)
                qw[g][c * 2 + j] = (unsigned)qweight[rb + (size_t)(c * 4) * NDIM + nc[j]];
    }

    // raw scales/zeros (loads only; convert later)
    float sraw[GPS][2];
    int   zraw[GPS][2];
    #pragma unroll
    for (int g = 0; g < GPS; ++g)
        #pragma unroll
        for (int j = 0; j < 2; ++j) {
            sraw[g][j] = scales[(size_t)(g0 + g) * NDIM + nc[j]];
            zraw[g][j] = qzeros[(size_t)(g0 + g) * NZW + (nc[j] >> 3)];
        }

    __builtin_amdgcn_sched_barrier(0);   // pin: prefetch issues before staging

    // ---- x staging: 8x global_load_lds(16B); LDS linear, src pre-swizzled
    //      so LDS content matches r5's XOR layout: L = (t*1024+kl*2)^((t&7)<<4)
    {
        #pragma unroll
        for (int it = 0; it < 8; ++it) {
            const int c = it * 256 + tid;            // dest 16B-chunk 0..2047
            const int v = c ^ ((c >> 6) & 7);        // src chunk (involution)
            const int t = c >> 6;                    // token row 0..31
            const _Float16* src = xp + (size_t)t * KDIM + kseg0 + (v & 63) * 8;
            __builtin_amdgcn_global_load_lds(
                (gas_void*)src,
                (las_void*)(xb + it * 4096 + wav * 1024),
                16, 0, 0);
        }
    }

    // convert scales/zeros while staging is in flight
    half2v sp[GPS][2], cp[GPS][2];
    #pragma unroll
    for (int g = 0; g < GPS; ++g)
        #pragma unroll
        for (int j = 0; j < 2; ++j) {
            const int z = (zraw[g][j] >> ((nc[j] & 7) * 4)) & 15;
            const _Float16 sh = (_Float16)sraw[g][j];
            const _Float16 ch = (_Float16)(float)(-(1025 + z));
            sp[g][j] = (half2v){sh, sh};
            cp[g][j] = (half2v){ch, ch};
        }

    __syncthreads();                     // drains vmcnt: staging + qw complete

    f32x4 acc[2][2];
    #pragma unroll
    for (int j = 0; j < 2; ++j)
        #pragma unroll
        for (int m = 0; m < 2; ++m)
            acc[j][m] = (f32x4){0.f, 0.f, 0.f, 0.f};

    // compute: registers + LDS only
    #pragma unroll
    for (int g = 0; g < GPS; ++g) {
        #pragma unroll
        for (int c = 0; c < 4; ++c) {
            const int kloc = g * 128 + c * 32 + quad * 8;
            const int o0 = (l16 * 1024 + kloc * 2) ^ ((l16 & 7) << 4);
            half8 a0 = *(const half8*)(xb + o0);
            half8 a1 = *(const half8*)(xb + o0 + 16 * 1024);  // row+16: same key
            #pragma unroll
            for (int j = 0; j < 2; ++j) {
                const unsigned w = qw[g][c * 2 + j];
                uint4v bu;
                #pragma unroll
                for (int i = 0; i < 4; ++i) {
                    unsigned t = ((w >> (4 * i)) & 0x000F000Fu) | 0x64006400u;
                    half2v th = __builtin_bit_cast(half2v, t);
                    half2v r  = (th + cp[g][j]) * sp[g][j];
                    bu[i] = __builtin_bit_cast(unsigned, r);
                }
                half8 bf = __builtin_bit_cast(half8, bu);
                acc[j][0] = __builtin_amdgcn_mfma_f32_16x16x32_f16(a0, bf, acc[j][0], 0, 0, 0);
                acc[j][1] = __builtin_amdgcn_mfma_f32_16x16x32_f16(a1, bf, acc[j][1], 0, 0, 0);
            }
        }
    }

    // epilogue: fp16 partials to ws
    _Float16* wsp = ws + (size_t)seg * (T_TOK * NDIM);
    #pragma unroll
    for (int j = 0; j < 2; ++j)
        #pragma unroll
        for (int m = 0; m < 2; ++m)
            #pragma unroll
            for (int r = 0; r < 4; ++r) {
                const int t = m * 16 + quad * 4 + r;
                wsp[(size_t)t * NDIM + nc[j]] = (_Float16)acc[j][m][r];
            }
}

__global__ __launch_bounds__(256)
void reduce_bias(const _Float16* __restrict__ ws,
                 const float*    __restrict__ bias,
                 float*          __restrict__ out)
{
    const int e = (blockIdx.x * 256 + threadIdx.x) * 8;  // 8 consecutive, one row
    const int n = e % NDIM;
    float sum[8] = {0.f, 0.f, 0.f, 0.f, 0.f, 0.f, 0.f, 0.f};
    #pragma unroll
    for (int s = 0; s < NSEG; ++s) {
        half8 v = *(const half8*)(ws + (size_t)s * (T_TOK * NDIM) + e);
        #pragma unroll
        for (int i = 0; i < 8; ++i) sum[i] += (float)v[i];
    }
    f32x4 o0, o1;
    #pragma unroll
    for (int i = 0; i < 4; ++i) {
        o0[i] = sum[i]     + bias[n + i];
        o1[i] = sum[i + 4] + bias[n + 4 + i];
    }
    *(f32x4*)(out + e)     = o0;
    *(f32x4*)(out + e + 4) = o1;
}

// ---- fallback (no usable ws): r5's single-barrier LDS kernel, atomics ----
__global__ __launch_bounds__(256)
void exllama_gemm_atomic(const int*   __restrict__ qweight,
                         const int*   __restrict__ qzeros,
                         const float* __restrict__ scales,
                         const float* __restrict__ x,
                         const float* __restrict__ bias,
                         float*       __restrict__ out)
{
    __shared__ alignas(16) _Float16 xs[T_TOK * SEGK];
    char* xb = (char*)xs;

    const int tid  = threadIdx.x;
    const int lane = tid & 63;
    const int wav  = tid >> 6;
    const int quad = lane >> 4;
    const int l16  = lane & 15;
    const int seg  = blockIdx.y;
    const int n0   = blockIdx.x * 128 + wav * 32;
    const int g0   = seg * GPS;

    int nc[2];
    nc[0] = n0 + l16;
    nc[1] = n0 + 16 + l16;

    unsigned qw[GPS][8];
    #pragma unroll
    for (int g = 0; g < GPS; ++g) {
        const size_t rb = (size_t)((g0 + g) * 16 + quad) * NDIM;
        #pragma unroll
        for (int c = 0; c < 4; ++c)
            #pragma unroll
            for (int j = 0; j < 2; ++j)
                qw[g][c * 2 + j] = (unsigned)qweight[rb + (size_t)(c * 4) * NDIM + nc[j]];
    }
    float sraw[GPS][2];
    int   zraw[GPS][2];
    #pragma unroll
    for (int g = 0; g < GPS; ++g)
        #pragma unroll
        for (int j = 0; j < 2; ++j) {
            sraw[g][j] = scales[(size_t)(g0 + g) * NDIM + nc[j]];
            zraw[g][j] = qzeros[(size_t)(g0 + g) * NZW + (nc[j] >> 3)];
        }
    {
        const int kseg0 = seg * SEGK;
        #pragma unroll
        for (int it = 0; it < 8; ++it) {
            const int e  = it * 2048 + tid * 8;
            const int t  = e >> 9;
            const int kl = e & (SEGK - 1);
            const float* xpr = x + (size_t)t * KDIM + kseg0 + kl;
            f32x4 lo = *(const f32x4*)xpr;
            f32x4 hi = *(const f32x4*)(xpr + 4);
            uint4v u;
            #pragma unroll
            for (int j = 0; j < 4; ++j)
                u[j] = __builtin_bit_cast(unsigned,
                          __builtin_amdgcn_cvt_pkrtz(lo[j], hi[j]));
            const int off = (t * 1024 + kl * 2) ^ ((t & 7) << 4);
            *(uint4v*)(xb + off) = u;
        }
    }
    half2v sp[GPS][2], cp[GPS][2];
    #pragma unroll
    for (int g = 0; g < GPS; ++g)
        #pragma unroll
        for (int j = 0; j < 2; ++j) {
            const int z = (zraw[g][j] >> ((nc[j] & 7) * 4)) & 15;
            const _Float16 sh = (_Float16)sraw[g][j];
            const _Float16 ch = (_Float16)(float)(-(1025 + z));
            sp[g][j] = (half2v){sh, sh};
            cp[g][j] = (half2v){ch, ch};
        }
    __syncthreads();

    f32x4 acc[2][2];
    #pragma unroll
    for (int j = 0; j < 2; ++j)
        #pragma unroll
        for (int m = 0; m < 2; ++m)
            acc[j][m] = (f32x4){0.f, 0.f, 0.f, 0.f};
    #pragma unroll
    for (int g = 0; g < GPS; ++g) {
        #pragma unroll
        for (int c = 0; c < 4; ++c) {
            const int kloc = g * 128 + c * 32 + quad * 8;
            const int o0 = (l16 * 1024 + kloc * 2) ^ ((l16 & 7) << 4);
            half8 a0 = *(const half8*)(xb + o0);
            half8 a1 = *(const half8*)(xb + o0 + 16 * 1024);
            #pragma unroll
            for (int j = 0; j < 2; ++j) {
                const unsigned w = qw[g][c * 2 + j];
                uint4v bu;
                #pragma unroll
                for (int i = 0; i < 4; ++i) {
                    unsigned t = ((w >> (4 * i)) & 0x000F000Fu) | 0x64006400u;
                    half2v th = __builtin_bit_cast(half2v, t);
                    half2v r  = (th + cp[g][j]) * sp[g][j];
                    bu[i] = __builtin_bit_cast(unsigned, r);
                }
                half8 bf = __builtin_bit_cast(half8, bu);
                acc[j][0] = __builtin_amdgcn_mfma_f32_16x16x32_f16(a0, bf, acc[j][0], 0, 0, 0);
                acc[j][1] = __builtin_amdgcn_mfma_f32_16x16x32_f16(a1, bf, acc[j][1], 0, 0, 0);
            }
        }
    }
    #pragma unroll
    for (int j = 0; j < 2; ++j) {
        const float bb = bias[nc[j]] * (1.0f / NSEG);
        #pragma unroll
        for (int m = 0; m < 2; ++m)
            #pragma unroll
            for (int r = 0; r < 4; ++r) {
                const int t = m * 16 + quad * 4 + r;
                unsafeAtomicAdd(out + (size_t)t * NDIM + nc[j], acc[j][m][r] + bb);
            }
    }
}

extern "C" void kernel_launch(void* const* d_in, const int* in_sizes, int n_in,
                              void* d_out, int out_size, void* d_ws, size_t ws_size,
                              hipStream_t stream)
{
    const float* x  = (const float*)d_in[0];   // (32, 8192) f32 (fp16 promoted)
    const int* qweight = (const int*)d_in[1];  // (1024, 28672) i32
    const int* qzeros  = (const int*)d_in[2];  // (64, 3584) i32
    const float* sc = (const float*)d_in[3];   // (64, 28672) f32
    const float* bs = (const float*)d_in[4];   // (28672,) f32
    float* out      = (float*)d_out;           // (32, 28672) f32

    const size_t xpbytes = (size_t)T_TOK * KDIM * sizeof(_Float16);        // 512 KB
    const size_t pbytes  = (size_t)NSEG * T_TOK * NDIM * sizeof(_Float16); // 29.4 MB
    if (ws_size >= xpbytes + pbytes) {
        _Float16* xp   = (_Float16*)d_ws;
        _Float16* part = xp + (size_t)T_TOK * KDIM;
        xprep<<<(T_TOK * KDIM / 8) / 256, 256, 0, stream>>>(x, xp);
        exllama_gemm_glds<<<dim3(NDIM / 128, NSEG), 256, 0, stream>>>(
            qweight, qzeros, sc, xp, part);
        reduce_bias<<<(T_TOK * NDIM) / (256 * 8), 256, 0, stream>>>(
            part, bs, out);
    } else {
        exllama_gemm_atomic<<<dim3(NDIM / 128, NSEG), 256, 0, stream>>>(
            qweight, qzeros, sc, x, bs, out);
    }
}